// Round 2
// baseline (174.377 us; speedup 1.0000x reference)
//
#include <hip/hip_runtime.h>
#include <cstdint>
#include <cstddef>

// ManualChebConv via Chebyshev composition:
//   M2 := T2(L) = 2L^2 - I  (precomputed, bf16, split-precision MFMA)
//   Round 1 (one K-pass over Z0): Z1 = L@Z0, Z2 = M2@Z0
//   Round 2 (one K-pass over Z2): S3 = 2L@Z2, S4 = 2M2@Z2
//   out = Z0@(W0-W4) + Z1@(W1-W3) + Z2@W2 + S3@W3 + S4@W4 + b
// (exact: Z3 = S3 - Z1, Z4 = S4 - Z0 folded into the weights -> no RMW writebacks,
//  serial GEMM depth 4 -> 2, LDS B-fragment reads halved: each B-frag feeds 2 A-streams.)
//
// B=1024, N=512, F_in=16, F_out=8. 1 block per 4 batches (256 blocks, 512 thr).
// Z kept in LDS as bf16 Z^T[col=64][n=512], stride 520. Two buffers; Z2 overwrites
// Z0 in place (full Z2 is in registers after the K-loop, written post-barrier).

typedef __attribute__((ext_vector_type(8))) short  frag_ab;  // 8 bf16
typedef __attribute__((ext_vector_type(4))) float  frag_cd;  // 4 fp32

constexpr int BN    = 512;        // N
constexpr int FIN   = 16;
constexpr int FOUT  = 8;
constexpr int BT    = 4;          // batches per block
constexpr int NCOLS = BT * FIN;   // 64 combined cols
constexpr int LDST  = BN + 8;     // padded stride (bank-friendly, 16B aligned)
constexpr int ZBUF  = NCOLS * LDST;

__device__ __forceinline__ uint16_t f2bf(float f) {
    uint32_t u = __builtin_bit_cast(uint32_t, f);
    u += 0x7FFFu + ((u >> 16) & 1u);          // round-to-nearest-even
    return (uint16_t)(u >> 16);
}
__device__ __forceinline__ float bf2f(uint16_t h) {
    uint32_t u = ((uint32_t)h) << 16;
    return __builtin_bit_cast(float, u);
}

__global__ void cvtL(const float* __restrict__ Lf, uint16_t* __restrict__ Lb) {
    int i = blockIdx.x * 256 + threadIdx.x;   // 1024 blocks x 256 = 262144
    Lb[i] = f2bf(Lf[i]);
}

// M2 = 2*L@L - I in bf16, from fp32 L. Split-bf16 (hi/lo) MFMA: error ~ one bf16
// rounding. L symmetric -> B-fragments read row-major: B[k][j] = L[j][k].
// 256 blocks x 256 thr; block -> 32x32 tile; wave w -> 16x16 sub-tile (w>>1, w&1).
__global__ __launch_bounds__(256)
void m2comp(const float* __restrict__ Lf, uint16_t* __restrict__ Mb) {
    const int tid = threadIdx.x;
    const int wv = tid >> 6, lane = tid & 63, lr = lane & 15, q = lane >> 4;
    const int i0 = (blockIdx.x >> 4) * 32 + (wv >> 1) * 16;
    const int j0 = (blockIdx.x & 15) * 32 + (wv & 1) * 16;
    frag_cd acc = {0.f, 0.f, 0.f, 0.f};
    const float* arow = Lf + (size_t)(i0 + lr) * BN;   // A[m][k] = L[i0+m][k]
    const float* brow = Lf + (size_t)(j0 + lr) * BN;   // B[k][n] = L[k][j0+n] = L[j0+n][k]
    for (int ks = 0; ks < 16; ++ks) {
        const int kb = ks * 32 + q * 8;
        const float4* ap = reinterpret_cast<const float4*>(arow + kb);
        const float4* bp = reinterpret_cast<const float4*>(brow + kb);
        float4 a0 = ap[0], a1 = ap[1], b0 = bp[0], b1 = bp[1];
        float av[8]  = {a0.x, a0.y, a0.z, a0.w, a1.x, a1.y, a1.z, a1.w};
        float bvv[8] = {b0.x, b0.y, b0.z, b0.w, b1.x, b1.y, b1.z, b1.w};
        frag_ab ah, al, bh, bl;
#pragma unroll
        for (int j = 0; j < 8; ++j) {
            uint16_t h = f2bf(av[j]);
            ah[j] = (short)h;
            al[j] = (short)f2bf(av[j] - bf2f(h));
            uint16_t g = f2bf(bvv[j]);
            bh[j] = (short)g;
            bl[j] = (short)f2bf(bvv[j] - bf2f(g));
        }
        acc = __builtin_amdgcn_mfma_f32_16x16x32_bf16(ah, bh, acc, 0, 0, 0);
        acc = __builtin_amdgcn_mfma_f32_16x16x32_bf16(ah, bl, acc, 0, 0, 0);
        acc = __builtin_amdgcn_mfma_f32_16x16x32_bf16(al, bh, acc, 0, 0, 0);
    }
    // D: col = lane&15 -> j-local, row = q*4+r -> i-local
#pragma unroll
    for (int r = 0; r < 4; ++r) {
        int i = i0 + q * 4 + r, j = j0 + lr;
        float v = 2.f * acc[r] - ((i == j) ? 1.f : 0.f);
        Mb[(size_t)i * BN + j] = f2bf(v);
    }
}

__global__ __launch_bounds__(512, 2)
void cheb2_kernel(const float* __restrict__ x, const uint16_t* __restrict__ Lb,
                  const uint16_t* __restrict__ Mb, const float* __restrict__ W,
                  const float* __restrict__ bvec, float* __restrict__ out) {
    __shared__ uint16_t lds[2 * ZBUF];        // 133,120 B
    uint16_t* z0 = lds;
    uint16_t* z1 = lds + ZBUF;

    const int tid  = threadIdx.x;
    const int wave = tid >> 6;                // 0..7
    const int lane = tid & 63;
    const int lr   = lane & 15;
    const int q    = lane >> 4;

    // ---------------- stage x -> Z0^T (bf16) in z0 ----------------
    const float4* x4 = reinterpret_cast<const float4*>(x + (size_t)blockIdx.x * (BT * BN * FIN));
    for (int s = 0; s < 2; ++s) {
        int a   = tid + s * 512;
        int f0g = a & 3;
        int n8  = (a >> 2) & 63;
        int bl  = a >> 8;
        int jb  = bl * 2048 + n8 * 32 + f0g;
        float4 v[8];
#pragma unroll
        for (int r = 0; r < 8; ++r) v[r] = x4[jb + r * 4];
        int cb = bl * 16 + f0g * 4;
        int nb = n8 * 8;
#pragma unroll
        for (int w = 0; w < 4; ++w) {
            frag_ab pk;
#pragma unroll
            for (int r = 0; r < 8; ++r)
                pk[r] = (short)f2bf(reinterpret_cast<const float*>(&v[r])[w]);
            *reinterpret_cast<frag_ab*>(&z0[(cb + w) * LDST + nb]) = pk;
        }
    }

    // ---------------- combined W pair B-fragments + bias ----------------
    // Effective weights: E0=W0-W4, E1=W1-W3, E2=W2, E3=W3, E4=W4, E5=0.
    // pair p: k<16 -> E[2p], k>=16 -> E[2p+1]; zero pad fo>=8.
    frag_ab wf[3];
#pragma unroll
    for (int p = 0; p < 3; ++p) {
        frag_ab t;
#pragma unroll
        for (int jj = 0; jj < 8; ++jj) {
            int k   = q * 8 + jj;
            int ki  = p * 2 + (k >> 4);
            int fin = k & 15;
            float val = 0.0f;
            if (lr < 8) {
                int idx = fin * FOUT + lr;
                if      (ki == 0) val = W[idx] - W[4 * (FIN * FOUT) + idx];
                else if (ki == 1) val = W[1 * (FIN * FOUT) + idx] - W[3 * (FIN * FOUT) + idx];
                else if (ki < 5)  val = W[ki * (FIN * FOUT) + idx];
            }
            t[jj] = (short)f2bf(val);
        }
        wf[p] = t;
    }
    const float bv = (lr < 8) ? bvec[lr] : 0.0f;

    frag_cd accOut[4][4] = {};                // [mtIdx][bt] out tiles (fp32)

    // A-fragment from a row-major bf16 [512][512] matrix
    auto loadA = [&](const uint16_t* M, int mt, int ks) -> frag_ab {
        return *reinterpret_cast<const frag_ab*>(M + (size_t)(mt * 16 + lr) * BN + ks * 32 + q * 8);
    };

    frag_cd acc1[4][4];                       // L  @ cur
    frag_cd acc2[4][4];                       // M2 @ cur

    // One fused K-pass: acc1 = L@cur, acc2 = M2@cur (shared B-fragments)
    auto round = [&](const uint16_t* cur) {
#pragma unroll
        for (int mi = 0; mi < 4; ++mi)
#pragma unroll
            for (int ct = 0; ct < 4; ++ct) {
                acc1[mi][ct] = (frag_cd){0.f, 0.f, 0.f, 0.f};
                acc2[mi][ct] = (frag_cd){0.f, 0.f, 0.f, 0.f};
            }
        for (int ks = 0; ks < 16; ++ks) {
            frag_ab bfr[4];
#pragma unroll
            for (int ct = 0; ct < 4; ++ct)
                bfr[ct] = *reinterpret_cast<const frag_ab*>(
                    cur + (ct * 16 + lr) * LDST + ks * 32 + q * 8);
#pragma unroll
            for (int mi = 0; mi < 4; ++mi) {
                frag_ab a = loadA(Lb, wave + mi * 8, ks);
                frag_ab m = loadA(Mb, wave + mi * 8, ks);
#pragma unroll
                for (int ct = 0; ct < 4; ++ct)
                    acc1[mi][ct] = __builtin_amdgcn_mfma_f32_16x16x32_bf16(
                        a, bfr[ct], acc1[mi][ct], 0, 0, 0);
#pragma unroll
                for (int ct = 0; ct < 4; ++ct)
                    acc2[mi][ct] = __builtin_amdgcn_mfma_f32_16x16x32_bf16(
                        m, bfr[ct], acc2[mi][ct], 0, 0, 0);
            }
        }
    };

    // Plain writeback: dst <- bf16(scale * acc)  (no RMW anywhere)
    auto wb = [&](frag_cd (&acc)[4][4], uint16_t* dst, float scale) {
#pragma unroll
        for (int mi = 0; mi < 4; ++mi) {
            int row0 = (wave + mi * 8) * 16 + q * 4;
#pragma unroll
            for (int ct = 0; ct < 4; ++ct) {
                uint16_t* dp = dst + (ct * 16 + lr) * LDST + row0;
                ushort4 nv;
                nv.x = f2bf(scale * acc[mi][ct][0]);
                nv.y = f2bf(scale * acc[mi][ct][1]);
                nv.z = f2bf(scale * acc[mi][ct][2]);
                nv.w = f2bf(scale * acc[mi][ct][3]);
                *reinterpret_cast<ushort4*>(dp) = nv;
            }
        }
    };

    // Paired epilogue: accOut += [bufA | bufB](A-layout) @ wfr
    auto epi = [&](const uint16_t* bA, const uint16_t* bB, frag_ab wfr) {
        const uint16_t* base = (q < 2) ? bA : bB;
        int finb = (q & 1) * 8;
#pragma unroll
        for (int mi = 0; mi < 4; ++mi) {
            int n = (wave + mi * 8) * 16 + lr;
#pragma unroll
            for (int bt = 0; bt < 4; ++bt) {
                const uint16_t* pp = base + (bt * 16 + finb) * LDST + n;
                frag_ab afr;
#pragma unroll
                for (int jj = 0; jj < 8; ++jj) afr[jj] = (short)pp[jj * LDST];
                accOut[mi][bt] = __builtin_amdgcn_mfma_f32_16x16x32_bf16(
                    afr, wfr, accOut[mi][bt], 0, 0, 0);
            }
        }
    };

    __syncthreads();                  // staging visible
    round(z0);                        // acc1 = Z1 = L@Z0, acc2 = Z2 = M2@Z0
    wb(acc1, z1, 1.f);                // z1 <- Z1 (z1 unread so far: no barrier needed)
    __syncthreads();                  // Z1 visible
    epi(z0, z1, wf[0]);               // accOut += Z0@(W0-W4) + Z1@(W1-W3)
    __syncthreads();                  // all z0 reads (K-pass + epi0) done
    wb(acc2, z0, 1.f);                // z0 <- Z2 (in-place over Z0)
    __syncthreads();                  // Z2 visible
    round(z0);                        // acc1 = L@Z2, acc2 = M2@Z2
    wb(acc1, z1, 2.f);                // z1 <- S3 = 2L@Z2 (z1 dead since epi0 barrier)
    __syncthreads();                  // S3 visible, K-pass z0 reads done
    epi(z0, z1, wf[1]);               // accOut += Z2@W2 + S3@W3
    __syncthreads();                  // epi1's z0 reads done
    wb(acc2, z0, 2.f);                // z0 <- S4 = 2M2@Z2
    __syncthreads();                  // S4 visible
    epi(z0, z0, wf[2]);               // accOut += S4@W4 (second-half weights zero)

    // ---------------- store ----------------
    if (lr < 8) {
        float* ob = out + (size_t)blockIdx.x * BT * BN * FOUT;
#pragma unroll
        for (int mi = 0; mi < 4; ++mi) {
            int row0 = (wave + mi * 8) * 16 + q * 4;
#pragma unroll
            for (int bt = 0; bt < 4; ++bt) {
                float* op = ob + bt * (BN * FOUT) + row0 * FOUT + lr;
                op[0 * FOUT] = accOut[mi][bt][0] + bv;
                op[1 * FOUT] = accOut[mi][bt][1] + bv;
                op[2 * FOUT] = accOut[mi][bt][2] + bv;
                op[3 * FOUT] = accOut[mi][bt][3] + bv;
            }
        }
    }
}

// ---------------- v1 fallback (4-app recurrence), used if ws too small ----------------
template <bool LBF16>
__global__ __launch_bounds__(512, 2)
void cheb1_kernel(const float* __restrict__ x, const float* __restrict__ Lf,
                  const uint16_t* __restrict__ Lb, const float* __restrict__ W,
                  const float* __restrict__ bvec, float* __restrict__ out) {
    __shared__ uint16_t lds[2 * ZBUF];
    uint16_t* z0 = lds;
    uint16_t* z1 = lds + ZBUF;

    const int tid  = threadIdx.x;
    const int wave = tid >> 6;
    const int lane = tid & 63;
    const int lr   = lane & 15;
    const int q    = lane >> 4;

    const float4* x4 = reinterpret_cast<const float4*>(x + (size_t)blockIdx.x * (BT * BN * FIN));
    for (int s = 0; s < 2; ++s) {
        int a   = tid + s * 512;
        int f0g = a & 3;
        int n8  = (a >> 2) & 63;
        int bl  = a >> 8;
        int jb  = bl * 2048 + n8 * 32 + f0g;
        float4 v[8];
#pragma unroll
        for (int r = 0; r < 8; ++r) v[r] = x4[jb + r * 4];
        int cb = bl * 16 + f0g * 4;
        int nb = n8 * 8;
#pragma unroll
        for (int w = 0; w < 4; ++w) {
            frag_ab pk;
#pragma unroll
            for (int r = 0; r < 8; ++r)
                pk[r] = (short)f2bf(reinterpret_cast<const float*>(&v[r])[w]);
            *reinterpret_cast<frag_ab*>(&z0[(cb + w) * LDST + nb]) = pk;
        }
    }

    frag_ab wf[3];
#pragma unroll
    for (int p = 0; p < 3; ++p) {
        frag_ab t;
#pragma unroll
        for (int jj = 0; jj < 8; ++jj) {
            int k   = q * 8 + jj;
            int ki  = p * 2 + (k >> 4);
            int fin = k & 15;
            float val = (lr < 8 && ki < 5) ? W[ki * (FIN * FOUT) + fin * FOUT + lr] : 0.0f;
            t[jj] = (short)f2bf(val);
        }
        wf[p] = t;
    }
    const float bv = (lr < 8) ? bvec[lr] : 0.0f;

    frag_cd accOut[4][4] = {};

    auto loadA = [&](int mt, int ks) -> frag_ab {
        int row = mt * 16 + lr;
        int kb  = ks * 32 + q * 8;
        if constexpr (LBF16) {
            return *reinterpret_cast<const frag_ab*>(Lb + row * BN + kb);
        } else {
            const float4* p  = reinterpret_cast<const float4*>(Lf + row * BN + kb);
            float4 u0 = p[0], u1 = p[1];
            frag_ab t;
            t[0] = (short)f2bf(u0.x); t[1] = (short)f2bf(u0.y);
            t[2] = (short)f2bf(u0.z); t[3] = (short)f2bf(u0.w);
            t[4] = (short)f2bf(u1.x); t[5] = (short)f2bf(u1.y);
            t[6] = (short)f2bf(u1.z); t[7] = (short)f2bf(u1.w);
            return t;
        }
    };

    auto app = [&](const uint16_t* cur, uint16_t* dst, bool first) {
        frag_cd acc[4][4] = {};
        for (int ks = 0; ks < 16; ++ks) {
            frag_ab bfr[4];
#pragma unroll
            for (int ct = 0; ct < 4; ++ct)
                bfr[ct] = *reinterpret_cast<const frag_ab*>(
                    cur + (ct * 16 + lr) * LDST + ks * 32 + q * 8);
#pragma unroll
            for (int mi = 0; mi < 4; ++mi) {
                frag_ab a = loadA(wave + mi * 8, ks);
#pragma unroll
                for (int ct = 0; ct < 4; ++ct)
                    acc[mi][ct] = __builtin_amdgcn_mfma_f32_16x16x32_bf16(
                        a, bfr[ct], acc[mi][ct], 0, 0, 0);
            }
        }
#pragma unroll
        for (int mi = 0; mi < 4; ++mi) {
            int row0 = (wave + mi * 8) * 16 + q * 4;
#pragma unroll
            for (int ct = 0; ct < 4; ++ct) {
                uint16_t* dp = dst + (ct * 16 + lr) * LDST + row0;
                float pz[4] = {0.f, 0.f, 0.f, 0.f};
                if (!first) {
                    ushort4 pv = *reinterpret_cast<const ushort4*>(dp);
                    pz[0] = bf2f(pv.x); pz[1] = bf2f(pv.y);
                    pz[2] = bf2f(pv.z); pz[3] = bf2f(pv.w);
                }
                ushort4 nv;
                float v0 = acc[mi][ct][0], v1 = acc[mi][ct][1];
                float v2 = acc[mi][ct][2], v3 = acc[mi][ct][3];
                if (!first) {
                    v0 = 2.f * v0 - pz[0]; v1 = 2.f * v1 - pz[1];
                    v2 = 2.f * v2 - pz[2]; v3 = 2.f * v3 - pz[3];
                }
                nv.x = f2bf(v0); nv.y = f2bf(v1); nv.z = f2bf(v2); nv.w = f2bf(v3);
                *reinterpret_cast<ushort4*>(dp) = nv;
            }
        }
    };

    auto epi = [&](const uint16_t* bA, const uint16_t* bB, frag_ab wfr) {
        const uint16_t* base = (q < 2) ? bA : bB;
        int finb = (q & 1) * 8;
#pragma unroll
        for (int mi = 0; mi < 4; ++mi) {
            int n = (wave + mi * 8) * 16 + lr;
#pragma unroll
            for (int bt = 0; bt < 4; ++bt) {
                const uint16_t* pp = base + (bt * 16 + finb) * LDST + n;
                frag_ab afr;
#pragma unroll
                for (int jj = 0; jj < 8; ++jj) afr[jj] = (short)pp[jj * LDST];
                accOut[mi][bt] = __builtin_amdgcn_mfma_f32_16x16x32_bf16(
                    afr, wfr, accOut[mi][bt], 0, 0, 0);
            }
        }
    };

    __syncthreads();
    app(z0, z1, true);
    __syncthreads();
    epi(z0, z1, wf[0]);
    __syncthreads();
    app(z1, z0, false);
    __syncthreads();
    app(z0, z1, false);
    __syncthreads();
    epi(z0, z1, wf[1]);
    __syncthreads();
    app(z1, z0, false);
    __syncthreads();
    epi(z0, z0, wf[2]);

    if (lr < 8) {
        float* ob = out + (size_t)blockIdx.x * BT * BN * FOUT;
#pragma unroll
        for (int mi = 0; mi < 4; ++mi) {
            int row0 = (wave + mi * 8) * 16 + q * 4;
#pragma unroll
            for (int bt = 0; bt < 4; ++bt) {
                float* op = ob + bt * (BN * FOUT) + row0 * FOUT + lr;
                op[0 * FOUT] = accOut[mi][bt][0] + bv;
                op[1 * FOUT] = accOut[mi][bt][1] + bv;
                op[2 * FOUT] = accOut[mi][bt][2] + bv;
                op[3 * FOUT] = accOut[mi][bt][3] + bv;
            }
        }
    }
}

extern "C" void kernel_launch(void* const* d_in, const int* in_sizes, int n_in,
                              void* d_out, int out_size, void* d_ws, size_t ws_size,
                              hipStream_t stream) {
    const float* x  = (const float*)d_in[0];   // [1024,512,16]
    const float* Lf = (const float*)d_in[1];   // [512,512]
    const float* W  = (const float*)d_in[2];   // [5,16,8]
    const float* bv = (const float*)d_in[3];   // [8]
    float* out = (float*)d_out;                // [1024,512,8]

    const size_t matB = (size_t)BN * BN * sizeof(uint16_t);   // 512 KiB

    if (ws_size >= 2 * matB) {
        // Primary path: Lb = bf16(L), Mb = bf16(2L^2 - I), depth-2 fused kernel.
        uint16_t* Lb = (uint16_t*)d_ws;
        uint16_t* Mb = Lb + (size_t)BN * BN;
        cvtL<<<dim3(1024), dim3(256), 0, stream>>>(Lf, Lb);
        m2comp<<<dim3(256), dim3(256), 0, stream>>>(Lf, Mb);
        cheb2_kernel<<<dim3(256), dim3(512), 0, stream>>>(x, Lb, Mb, W, bv, out);
    } else if (ws_size >= matB) {
        uint16_t* Lb = (uint16_t*)d_ws;
        cvtL<<<dim3(1024), dim3(256), 0, stream>>>(Lf, Lb);
        cheb1_kernel<true><<<dim3(256), dim3(512), 0, stream>>>(x, Lf, Lb, W, bv, out);
    } else {
        cheb1_kernel<false><<<dim3(256), dim3(512), 0, stream>>>(x, Lf, nullptr, W, bv, out);
    }
}

// Round 3
// 145.991 us; speedup vs baseline: 1.1944x; 1.1944x over previous
//
#include <hip/hip_runtime.h>
#include <cstdint>
#include <cstddef>

// ManualChebConv via Chebyshev composition, v3: coalesced A-fragments.
//   M2 := T2(L) = 2L^2 - I  (precomputed bf16, split-precision MFMA)
//   Round 1: Z1 = L@Z0, Z2 = M2@Z0   (one K-pass, shared B-frags)
//   Round 2: S3 = 2L@Z2, S4 = 2M2@Z2
//   out = Z0@(W0-W4) + Z1@(W1-W3) + Z2@W2 + S3@W3 + S4@W4 + b
//
// v3 change (post-mortem of v2): runtime was invariant under serial-depth and
// LDS-traffic reduction -> bottleneck is the divergent A-fragment global loads
// (16 lanes x 1KB-apart rows = 16 cache lines per load) + scattered output
// stores (46MB WRITE_SIZE for a 17MB output). Fix: store L/M2 in the workspace
// PRE-SWIZZLED into per-lane fragment order so every loadA is a dense 1KB burst,
// and route the output through LDS for dense float4 stores.

typedef __attribute__((ext_vector_type(8))) short  frag_ab;  // 8 bf16
typedef __attribute__((ext_vector_type(4))) float  frag_cd;  // 4 fp32

constexpr int BN    = 512;        // N
constexpr int FIN   = 16;
constexpr int FOUT  = 8;
constexpr int BT    = 4;          // batches per block
constexpr int NCOLS = BT * FIN;   // 64 combined cols
constexpr int LDST  = BN + 8;     // padded stride (bank-friendly, 16B aligned)
constexpr int ZBUF  = NCOLS * LDST;   // 33280 u16 = 66,560 B (>= 64KB, reused as fp32 out-stage)

__device__ __forceinline__ uint16_t f2bf(float f) {
    uint32_t u = __builtin_bit_cast(uint32_t, f);
    u += 0x7FFFu + ((u >> 16) & 1u);          // round-to-nearest-even
    return (uint16_t)(u >> 16);
}
__device__ __forceinline__ float bf2f(uint16_t h) {
    uint32_t u = ((uint32_t)h) << 16;
    return __builtin_bit_cast(float, u);
}

// Fragment-order ("swizzled") index for an A-matrix element (row, k):
// fragment f = (row/16)*16 + (k/32); lane = ((k>>3)&3)*16 + (row&15); elem j = k&7.
// Linear: f*512 + lane*8 + j  -> each (mt,ks) fragment is a contiguous 1KB block
// read as lane*16B (perfectly coalesced).
__device__ __forceinline__ size_t aswz(int row, int k) {
    return ((size_t)((row >> 4) * 16 + (k >> 5)) * 64
            + ((k >> 3) & 3) * 16 + (row & 15)) * 8 + (k & 7);
}

// Row-major bf16 conversion (fallback path only)
__global__ void cvtL_rm(const float* __restrict__ Lf, uint16_t* __restrict__ Lb) {
    int i = blockIdx.x * 256 + threadIdx.x;   // 1024 x 256 = 262144
    Lb[i] = f2bf(Lf[i]);
}

// Swizzled bf16 conversion: thread t produces one lane-fragment (8 contiguous
// bf16 at output t*8). Output fully coalesced; divergent input reads are a
// one-time 1MB cost.
__global__ __launch_bounds__(256)
void cvtL_swz(const float* __restrict__ Lf, uint16_t* __restrict__ Lb) {
    int t = blockIdx.x * 256 + threadIdx.x;   // 128 x 256 = 32768
    int f = t >> 6, lane = t & 63;
    int mt = f >> 4, ks = f & 15;
    int row = mt * 16 + (lane & 15);
    int k0  = ks * 32 + (lane >> 4) * 8;
    const float4* p = reinterpret_cast<const float4*>(Lf + (size_t)row * BN + k0);
    float4 u0 = p[0], u1 = p[1];
    frag_ab o;
    o[0] = (short)f2bf(u0.x); o[1] = (short)f2bf(u0.y);
    o[2] = (short)f2bf(u0.z); o[3] = (short)f2bf(u0.w);
    o[4] = (short)f2bf(u1.x); o[5] = (short)f2bf(u1.y);
    o[6] = (short)f2bf(u1.z); o[7] = (short)f2bf(u1.w);
    *reinterpret_cast<frag_ab*>(Lb + (size_t)t * 8) = o;
}

// M2 = 2*L@L - I in bf16 (swizzled output), from fp32 L. Split-bf16 (hi/lo)
// MFMA: error ~ one bf16 rounding. L symmetric -> B[k][j] = L[j][k] readable
// row-major. 256 blocks x 256 thr; block -> 32x32 tile.
__global__ __launch_bounds__(256)
void m2comp(const float* __restrict__ Lf, uint16_t* __restrict__ Mb) {
    const int tid = threadIdx.x;
    const int wv = tid >> 6, lane = tid & 63, lr = lane & 15, q = lane >> 4;
    const int i0 = (blockIdx.x >> 4) * 32 + (wv >> 1) * 16;
    const int j0 = (blockIdx.x & 15) * 32 + (wv & 1) * 16;
    frag_cd acc = {0.f, 0.f, 0.f, 0.f};
    const float* arow = Lf + (size_t)(i0 + lr) * BN;   // A[m][k] = L[i0+m][k]
    const float* brow = Lf + (size_t)(j0 + lr) * BN;   // B[k][n] = L[j0+n][k]
    for (int ks = 0; ks < 16; ++ks) {
        const int kb = ks * 32 + q * 8;
        const float4* ap = reinterpret_cast<const float4*>(arow + kb);
        const float4* bp = reinterpret_cast<const float4*>(brow + kb);
        float4 a0 = ap[0], a1 = ap[1], b0 = bp[0], b1 = bp[1];
        float av[8]  = {a0.x, a0.y, a0.z, a0.w, a1.x, a1.y, a1.z, a1.w};
        float bvv[8] = {b0.x, b0.y, b0.z, b0.w, b1.x, b1.y, b1.z, b1.w};
        frag_ab ah, al, bh, bl;
#pragma unroll
        for (int j = 0; j < 8; ++j) {
            uint16_t h = f2bf(av[j]);
            ah[j] = (short)h;
            al[j] = (short)f2bf(av[j] - bf2f(h));
            uint16_t g = f2bf(bvv[j]);
            bh[j] = (short)g;
            bl[j] = (short)f2bf(bvv[j] - bf2f(g));
        }
        acc = __builtin_amdgcn_mfma_f32_16x16x32_bf16(ah, bh, acc, 0, 0, 0);
        acc = __builtin_amdgcn_mfma_f32_16x16x32_bf16(ah, bl, acc, 0, 0, 0);
        acc = __builtin_amdgcn_mfma_f32_16x16x32_bf16(al, bh, acc, 0, 0, 0);
    }
    // D: col = lane&15 -> j-local, row = q*4+r -> i-local; store swizzled
#pragma unroll
    for (int r = 0; r < 4; ++r) {
        int i = i0 + q * 4 + r, j = j0 + lr;
        float v = 2.f * acc[r] - ((i == j) ? 1.f : 0.f);
        Mb[aswz(i, j)] = f2bf(v);
    }
}

__global__ __launch_bounds__(512, 2)
void cheb2_kernel(const float* __restrict__ x, const uint16_t* __restrict__ Lb,
                  const uint16_t* __restrict__ Mb, const float* __restrict__ W,
                  const float* __restrict__ bvec, float* __restrict__ out) {
    __shared__ uint16_t lds[2 * ZBUF];        // 133,120 B
    uint16_t* z0 = lds;
    uint16_t* z1 = lds + ZBUF;

    const int tid  = threadIdx.x;
    const int wave = tid >> 6;                // 0..7
    const int lane = tid & 63;
    const int lr   = lane & 15;
    const int q    = lane >> 4;

    // ---------------- stage x -> Z0^T (bf16) in z0 ----------------
    const float4* x4 = reinterpret_cast<const float4*>(x + (size_t)blockIdx.x * (BT * BN * FIN));
    for (int s = 0; s < 2; ++s) {
        int a   = tid + s * 512;
        int f0g = a & 3;
        int n8  = (a >> 2) & 63;
        int bl  = a >> 8;
        int jb  = bl * 2048 + n8 * 32 + f0g;
        float4 v[8];
#pragma unroll
        for (int r = 0; r < 8; ++r) v[r] = x4[jb + r * 4];
        int cb = bl * 16 + f0g * 4;
        int nb = n8 * 8;
#pragma unroll
        for (int w = 0; w < 4; ++w) {
            frag_ab pk;
#pragma unroll
            for (int r = 0; r < 8; ++r)
                pk[r] = (short)f2bf(reinterpret_cast<const float*>(&v[r])[w]);
            *reinterpret_cast<frag_ab*>(&z0[(cb + w) * LDST + nb]) = pk;
        }
    }

    // ---------------- combined W pair B-fragments + bias ----------------
    // Effective weights: E0=W0-W4, E1=W1-W3, E2=W2, E3=W3, E4=W4, E5=0.
    frag_ab wf[3];
#pragma unroll
    for (int p = 0; p < 3; ++p) {
        frag_ab t;
#pragma unroll
        for (int jj = 0; jj < 8; ++jj) {
            int k   = q * 8 + jj;
            int ki  = p * 2 + (k >> 4);
            int fin = k & 15;
            float val = 0.0f;
            if (lr < 8) {
                int idx = fin * FOUT + lr;
                if      (ki == 0) val = W[idx] - W[4 * (FIN * FOUT) + idx];
                else if (ki == 1) val = W[1 * (FIN * FOUT) + idx] - W[3 * (FIN * FOUT) + idx];
                else if (ki < 5)  val = W[ki * (FIN * FOUT) + idx];
            }
            t[jj] = (short)f2bf(val);
        }
        wf[p] = t;
    }
    const float bv = (lr < 8) ? bvec[lr] : 0.0f;

    frag_cd accOut[4][4] = {};                // [mtIdx][bt] out tiles (fp32)

    // A-fragment from swizzled layout: dense 1KB burst, lane*16B contiguous.
    auto loadA = [&](const uint16_t* M, int mt, int ks) -> frag_ab {
        return *reinterpret_cast<const frag_ab*>(
            M + ((size_t)(mt * 16 + ks) * 64 + lane) * 8);
    };

    frag_cd acc1[4][4];                       // L  @ cur
    frag_cd acc2[4][4];                       // M2 @ cur

    // One fused K-pass: acc1 = L@cur, acc2 = M2@cur (shared B-fragments)
    auto round = [&](const uint16_t* cur) {
#pragma unroll
        for (int mi = 0; mi < 4; ++mi)
#pragma unroll
            for (int ct = 0; ct < 4; ++ct) {
                acc1[mi][ct] = (frag_cd){0.f, 0.f, 0.f, 0.f};
                acc2[mi][ct] = (frag_cd){0.f, 0.f, 0.f, 0.f};
            }
        for (int ks = 0; ks < 16; ++ks) {
            frag_ab bfr[4];
#pragma unroll
            for (int ct = 0; ct < 4; ++ct)
                bfr[ct] = *reinterpret_cast<const frag_ab*>(
                    cur + (ct * 16 + lr) * LDST + ks * 32 + q * 8);
#pragma unroll
            for (int mi = 0; mi < 4; ++mi) {
                frag_ab a = loadA(Lb, wave + mi * 8, ks);
                frag_ab m = loadA(Mb, wave + mi * 8, ks);
#pragma unroll
                for (int ct = 0; ct < 4; ++ct)
                    acc1[mi][ct] = __builtin_amdgcn_mfma_f32_16x16x32_bf16(
                        a, bfr[ct], acc1[mi][ct], 0, 0, 0);
#pragma unroll
                for (int ct = 0; ct < 4; ++ct)
                    acc2[mi][ct] = __builtin_amdgcn_mfma_f32_16x16x32_bf16(
                        m, bfr[ct], acc2[mi][ct], 0, 0, 0);
            }
        }
    };

    // Plain writeback: dst <- bf16(scale * acc)  (no RMW anywhere)
    auto wb = [&](frag_cd (&acc)[4][4], uint16_t* dst, float scale) {
#pragma unroll
        for (int mi = 0; mi < 4; ++mi) {
            int row0 = (wave + mi * 8) * 16 + q * 4;
#pragma unroll
            for (int ct = 0; ct < 4; ++ct) {
                uint16_t* dp = dst + (ct * 16 + lr) * LDST + row0;
                ushort4 nv;
                nv.x = f2bf(scale * acc[mi][ct][0]);
                nv.y = f2bf(scale * acc[mi][ct][1]);
                nv.z = f2bf(scale * acc[mi][ct][2]);
                nv.w = f2bf(scale * acc[mi][ct][3]);
                *reinterpret_cast<ushort4*>(dp) = nv;
            }
        }
    };

    // Paired epilogue: accOut += [bufA | bufB](A-layout) @ wfr
    auto epi = [&](const uint16_t* bA, const uint16_t* bB, frag_ab wfr) {
        const uint16_t* base = (q < 2) ? bA : bB;
        int finb = (q & 1) * 8;
#pragma unroll
        for (int mi = 0; mi < 4; ++mi) {
            int n = (wave + mi * 8) * 16 + lr;
#pragma unroll
            for (int bt = 0; bt < 4; ++bt) {
                const uint16_t* pp = base + (bt * 16 + finb) * LDST + n;
                frag_ab afr;
#pragma unroll
                for (int jj = 0; jj < 8; ++jj) afr[jj] = (short)pp[jj * LDST];
                accOut[mi][bt] = __builtin_amdgcn_mfma_f32_16x16x32_bf16(
                    afr, wfr, accOut[mi][bt], 0, 0, 0);
            }
        }
    };

    __syncthreads();                  // staging visible
    round(z0);                        // acc1 = Z1 = L@Z0, acc2 = Z2 = M2@Z0
    wb(acc1, z1, 1.f);                // z1 <- Z1 (z1 unread so far: no barrier needed)
    __syncthreads();                  // Z1 visible
    epi(z0, z1, wf[0]);               // accOut += Z0@(W0-W4) + Z1@(W1-W3)
    __syncthreads();                  // all z0 reads (K-pass + epi0) done
    wb(acc2, z0, 1.f);                // z0 <- Z2 (in-place over Z0)
    __syncthreads();                  // Z2 visible
    round(z0);                        // acc1 = L@Z2, acc2 = M2@Z2
    wb(acc1, z1, 2.f);                // z1 <- S3 = 2L@Z2 (z1 dead since epi0 barrier)
    __syncthreads();                  // S3 visible, K-pass z0 reads done
    epi(z0, z1, wf[1]);               // accOut += Z2@W2 + S3@W3
    __syncthreads();                  // epi1's z0 reads done (z1 also dead after this)
    wb(acc2, z0, 2.f);                // z0 <- S4 = 2M2@Z2
    __syncthreads();                  // S4 visible
    epi(z0, z0, wf[2]);               // accOut += S4@W4 (second-half weights zero)

    // ---------------- store via LDS (dense float4 bursts) ----------------
    // z1 is dead (last read in epi1, >=2 barriers ago). Stage [bt][n][fo] fp32
    // (65,536 B <= ZBUF's 66,560 B), then 8 coalesced float4 stores/thread.
    float* fbuf = reinterpret_cast<float*>(z1);
    if (lr < 8) {
#pragma unroll
        for (int mi = 0; mi < 4; ++mi) {
            int n0 = (wave + mi * 8) * 16 + q * 4;
#pragma unroll
            for (int bt = 0; bt < 4; ++bt) {
#pragma unroll
                for (int r = 0; r < 4; ++r)
                    fbuf[(bt * BN + n0 + r) * FOUT + lr] = accOut[mi][bt][r] + bv;
            }
        }
    }
    __syncthreads();
    {
        const float4* fb4 = reinterpret_cast<const float4*>(fbuf);
        float4* o4 = reinterpret_cast<float4*>(out + (size_t)blockIdx.x * (BT * BN * FOUT));
#pragma unroll
        for (int i = 0; i < 8; ++i)
            o4[i * 512 + tid] = fb4[i * 512 + tid];
    }
}

// ---------------- v1 fallback (4-app recurrence), used if ws too small ----------------
template <bool LBF16>
__global__ __launch_bounds__(512, 2)
void cheb1_kernel(const float* __restrict__ x, const float* __restrict__ Lf,
                  const uint16_t* __restrict__ Lb, const float* __restrict__ W,
                  const float* __restrict__ bvec, float* __restrict__ out) {
    __shared__ uint16_t lds[2 * ZBUF];
    uint16_t* z0 = lds;
    uint16_t* z1 = lds + ZBUF;

    const int tid  = threadIdx.x;
    const int wave = tid >> 6;
    const int lane = tid & 63;
    const int lr   = lane & 15;
    const int q    = lane >> 4;

    const float4* x4 = reinterpret_cast<const float4*>(x + (size_t)blockIdx.x * (BT * BN * FIN));
    for (int s = 0; s < 2; ++s) {
        int a   = tid + s * 512;
        int f0g = a & 3;
        int n8  = (a >> 2) & 63;
        int bl  = a >> 8;
        int jb  = bl * 2048 + n8 * 32 + f0g;
        float4 v[8];
#pragma unroll
        for (int r = 0; r < 8; ++r) v[r] = x4[jb + r * 4];
        int cb = bl * 16 + f0g * 4;
        int nb = n8 * 8;
#pragma unroll
        for (int w = 0; w < 4; ++w) {
            frag_ab pk;
#pragma unroll
            for (int r = 0; r < 8; ++r)
                pk[r] = (short)f2bf(reinterpret_cast<const float*>(&v[r])[w]);
            *reinterpret_cast<frag_ab*>(&z0[(cb + w) * LDST + nb]) = pk;
        }
    }

    frag_ab wf[3];
#pragma unroll
    for (int p = 0; p < 3; ++p) {
        frag_ab t;
#pragma unroll
        for (int jj = 0; jj < 8; ++jj) {
            int k   = q * 8 + jj;
            int ki  = p * 2 + (k >> 4);
            int fin = k & 15;
            float val = (lr < 8 && ki < 5) ? W[ki * (FIN * FOUT) + fin * FOUT + lr] : 0.0f;
            t[jj] = (short)f2bf(val);
        }
        wf[p] = t;
    }
    const float bv = (lr < 8) ? bvec[lr] : 0.0f;

    frag_cd accOut[4][4] = {};

    auto loadA = [&](int mt, int ks) -> frag_ab {
        int row = mt * 16 + lr;
        int kb  = ks * 32 + q * 8;
        if constexpr (LBF16) {
            return *reinterpret_cast<const frag_ab*>(Lb + row * BN + kb);
        } else {
            const float4* p  = reinterpret_cast<const float4*>(Lf + row * BN + kb);
            float4 u0 = p[0], u1 = p[1];
            frag_ab t;
            t[0] = (short)f2bf(u0.x); t[1] = (short)f2bf(u0.y);
            t[2] = (short)f2bf(u0.z); t[3] = (short)f2bf(u0.w);
            t[4] = (short)f2bf(u1.x); t[5] = (short)f2bf(u1.y);
            t[6] = (short)f2bf(u1.z); t[7] = (short)f2bf(u1.w);
            return t;
        }
    };

    auto app = [&](const uint16_t* cur, uint16_t* dst, bool first) {
        frag_cd acc[4][4] = {};
        for (int ks = 0; ks < 16; ++ks) {
            frag_ab bfr[4];
#pragma unroll
            for (int ct = 0; ct < 4; ++ct)
                bfr[ct] = *reinterpret_cast<const frag_ab*>(
                    cur + (ct * 16 + lr) * LDST + ks * 32 + q * 8);
#pragma unroll
            for (int mi = 0; mi < 4; ++mi) {
                frag_ab a = loadA(wave + mi * 8, ks);
#pragma unroll
                for (int ct = 0; ct < 4; ++ct)
                    acc[mi][ct] = __builtin_amdgcn_mfma_f32_16x16x32_bf16(
                        a, bfr[ct], acc[mi][ct], 0, 0, 0);
            }
        }
#pragma unroll
        for (int mi = 0; mi < 4; ++mi) {
            int row0 = (wave + mi * 8) * 16 + q * 4;
#pragma unroll
            for (int ct = 0; ct < 4; ++ct) {
                uint16_t* dp = dst + (ct * 16 + lr) * LDST + row0;
                float pz[4] = {0.f, 0.f, 0.f, 0.f};
                if (!first) {
                    ushort4 pv = *reinterpret_cast<const ushort4*>(dp);
                    pz[0] = bf2f(pv.x); pz[1] = bf2f(pv.y);
                    pz[2] = bf2f(pv.z); pz[3] = bf2f(pv.w);
                }
                ushort4 nv;
                float v0 = acc[mi][ct][0], v1 = acc[mi][ct][1];
                float v2 = acc[mi][ct][2], v3 = acc[mi][ct][3];
                if (!first) {
                    v0 = 2.f * v0 - pz[0]; v1 = 2.f * v1 - pz[1];
                    v2 = 2.f * v2 - pz[2]; v3 = 2.f * v3 - pz[3];
                }
                nv.x = f2bf(v0); nv.y = f2bf(v1); nv.z = f2bf(v2); nv.w = f2bf(v3);
                *reinterpret_cast<ushort4*>(dp) = nv;
            }
        }
    };

    auto epi = [&](const uint16_t* bA, const uint16_t* bB, frag_ab wfr) {
        const uint16_t* base = (q < 2) ? bA : bB;
        int finb = (q & 1) * 8;
#pragma unroll
        for (int mi = 0; mi < 4; ++mi) {
            int n = (wave + mi * 8) * 16 + lr;
#pragma unroll
            for (int bt = 0; bt < 4; ++bt) {
                const uint16_t* pp = base + (bt * 16 + finb) * LDST + n;
                frag_ab afr;
#pragma unroll
                for (int jj = 0; jj < 8; ++jj) afr[jj] = (short)pp[jj * LDST];
                accOut[mi][bt] = __builtin_amdgcn_mfma_f32_16x16x32_bf16(
                    afr, wfr, accOut[mi][bt], 0, 0, 0);
            }
        }
    };

    __syncthreads();
    app(z0, z1, true);
    __syncthreads();
    epi(z0, z1, wf[0]);
    __syncthreads();
    app(z1, z0, false);
    __syncthreads();
    app(z0, z1, false);
    __syncthreads();
    epi(z0, z1, wf[1]);
    __syncthreads();
    app(z1, z0, false);
    __syncthreads();
    epi(z0, z0, wf[2]);

    if (lr < 8) {
        float* ob = out + (size_t)blockIdx.x * BT * BN * FOUT;
#pragma unroll
        for (int mi = 0; mi < 4; ++mi) {
            int row0 = (wave + mi * 8) * 16 + q * 4;
#pragma unroll
            for (int bt = 0; bt < 4; ++bt) {
                float* op = ob + bt * (BN * FOUT) + row0 * FOUT + lr;
                op[0 * FOUT] = accOut[mi][bt][0] + bv;
                op[1 * FOUT] = accOut[mi][bt][1] + bv;
                op[2 * FOUT] = accOut[mi][bt][2] + bv;
                op[3 * FOUT] = accOut[mi][bt][3] + bv;
            }
        }
    }
}

extern "C" void kernel_launch(void* const* d_in, const int* in_sizes, int n_in,
                              void* d_out, int out_size, void* d_ws, size_t ws_size,
                              hipStream_t stream) {
    const float* x  = (const float*)d_in[0];   // [1024,512,16]
    const float* Lf = (const float*)d_in[1];   // [512,512]
    const float* W  = (const float*)d_in[2];   // [5,16,8]
    const float* bv = (const float*)d_in[3];   // [8]
    float* out = (float*)d_out;                // [1024,512,8]

    const size_t matB = (size_t)BN * BN * sizeof(uint16_t);   // 512 KiB

    if (ws_size >= 2 * matB) {
        // Primary path: swizzled Lb = bf16(L), Mb = bf16(2L^2 - I), depth-2 kernel.
        uint16_t* Lb = (uint16_t*)d_ws;
        uint16_t* Mb = Lb + (size_t)BN * BN;
        cvtL_swz<<<dim3(128), dim3(256), 0, stream>>>(Lf, Lb);
        m2comp<<<dim3(256), dim3(256), 0, stream>>>(Lf, Mb);
        cheb2_kernel<<<dim3(256), dim3(512), 0, stream>>>(x, Lb, Mb, W, bv, out);
    } else if (ws_size >= matB) {
        uint16_t* Lb = (uint16_t*)d_ws;
        cvtL_rm<<<dim3(1024), dim3(256), 0, stream>>>(Lf, Lb);
        cheb1_kernel<true><<<dim3(256), dim3(512), 0, stream>>>(x, Lf, Lb, W, bv, out);
    } else {
        cheb1_kernel<false><<<dim3(256), dim3(512), 0, stream>>>(x, Lf, nullptr, W, bv, out);
    }
}